// Round 14
// baseline (101.858 us; speedup 1.0000x reference)
//
#include <hip/hip_runtime.h>

typedef unsigned int uint;
typedef unsigned short ushort;
typedef __attribute__((ext_vector_type(8))) short short8;
typedef __attribute__((ext_vector_type(16))) float f32x16;
typedef __attribute__((ext_vector_type(4))) float float4v;
typedef __attribute__((ext_vector_type(4))) ushort ushort4v;

constexpr int Edim = 768;
constexpr int Kdim = 768;   // C*P*P
constexpr int Mdim = 25088; // B*Npatch
constexpr int BM = 256, BN = 128, BK = 32;
constexpr int KSTEPS = Kdim / BK;        // 24
constexpr int MB_TILES = Mdim / BM;      // 98
constexpr int EB_TILES = Edim / BN;      // 6
constexpr int NWG = MB_TILES * EB_TILES; // 588

// ws layout (r10-compatible)
constexpr size_t WS_AMAXARR = 0;            // NWG floats
constexpr size_t WS_WSF = 8192;
constexpr size_t WS_BIAS = 12288;
constexpr size_t WS_WINT = 16384;           // bf16 W [E][K] 768*768*2
constexpr size_t WS_APAT = 16384 + 1179648; // 25088*768*2 bf16 A
constexpr size_t WS_PQ = WS_APAT + (size_t)Mdim * Kdim * 2; // bf16 preout
constexpr size_t WS_NEED = WS_PQ + (size_t)Mdim * Edim * 2;

// round-to-nearest-even f32 -> bf16
__device__ __forceinline__ ushort f2bf(float f) {
  uint u = __float_as_uint(f);
  return (ushort)((u + 0x7fffu + ((u >> 16) & 1u)) >> 16);
}
__device__ __forceinline__ float bf2f(ushort b) {
  return __uint_as_float(((uint)b) << 16);
}

__device__ __forceinline__ void gload16(const void* g, void* l) {
  auto gp = (const __attribute__((address_space(1))) uint*)g;
  auto lp = (__attribute__((address_space(3))) uint*)l;
  __builtin_amdgcn_global_load_lds(gp, lp, 16, 0, 0);
}

// ---------------- fused: weight quant (blocks 0..767) + patchify ------------
__global__ void prep_patch_kernel(const float* __restrict__ weight,
                                  const float* __restrict__ bias,
                                  const float* __restrict__ sfin,
                                  ushort* __restrict__ w_int,
                                  float* __restrict__ w_sf,
                                  float* __restrict__ bias_out,
                                  const float* __restrict__ x,
                                  ushort* __restrict__ A, int n4) {
  const int t = threadIdx.x;
  if (blockIdx.x < Edim) {
    __shared__ float red[256];
    const int e = blockIdx.x;
    const float* wrow = weight + e * Kdim;
    float mx = 0.f;
    for (int k = t; k < Kdim; k += 256) mx = fmaxf(mx, fabsf(wrow[k]));
    red[t] = mx;
    __syncthreads();
    for (int s = 128; s > 0; s >>= 1) {
      if (t < s) red[t] = fmaxf(red[t], red[t + s]);
      __syncthreads();
    }
    const float sf = red[0] / 127.0f;
    for (int k = t; k < Kdim; k += 256)
      w_int[e * Kdim + k] = f2bf(rintf(wrow[k] / sf));
    if (t == 0) {
      float conv = sf * sfin[0];
      w_sf[e] = sf;
      bias_out[e] = rintf(bias[e] / conv) * conv;
    }
  } else {
    const int nb = gridDim.x - Edim;
    const int stride = nb * 256;
    for (int i4 = (blockIdx.x - Edim) * 256 + t; i4 < n4; i4 += stride) {
      const int i = i4 * 4;
      const int w = i % 224;
      const int t1 = i / 224;
      const int h = t1 % 224;
      const int t2 = t1 / 224;
      const int c = t2 % 3;
      const int b = t2 / 3;
      float4v v = *(const float4v*)(x + i);
      ushort4v u;
      u.x = f2bf(v.x); u.y = f2bf(v.y); u.z = f2bf(v.z); u.w = f2bf(v.w);
      const int m = b * 196 + (h >> 4) * 14 + (w >> 4);
      const int d = c * 256 + (h & 15) * 16 + (w & 15);
      *(ushort4v*)(A + m * Kdim + d) = u;
    }
  }
}

// ---------------- GEMM: 256x128, BK=32, 3-stage 72KB -> 2 blocks/CU ---------
// Hypothesis: per-CU VMEM instruction rate (~100 cyc/instr at 8 waves) is the
// wall; 2 co-resident blocks (16 waves) pipeline the TA like m97 (~44).
// LDS rows 32 bf16 (64B); 16B chunks, 4/row; stored slot = cb ^ (row&3);
// global_load_lds dest linear -> source pre-swizzled with same involution.
// Per step: issue 3 loads (tile kb+2), 8 ds_read, 8 MFMA 32x32x16_bf16,
// end {s_waitcnt vmcnt(3); s_barrier} -> tile kb+1 landed for all waves.
// Runtime loop (unroll 1) + stage-pointer rotation keeps icache small.
template <bool BF16OUT>
__global__ __launch_bounds__(512, 4) void gemm11_kernel(
    const ushort* __restrict__ A, const ushort* __restrict__ Bw,
    const float* __restrict__ w_sf, const float* __restrict__ bias_out,
    float* __restrict__ out, ushort* __restrict__ pq,
    float* __restrict__ amax_arr) {
  __shared__ __align__(16) ushort As[3][BM * BK]; // 3 x 16 KB
  __shared__ __align__(16) ushort Bs[3][BN * BK]; // 3 x  8 KB  (72 KB total)
  __shared__ float sred[8];

  const int t = threadIdx.x;
  // bijective XCD swizzle for NWG=588 (m204 variant)
  const int qq = NWG >> 3, r8 = NWG & 7;
  const int xcd = blockIdx.x & 7, bidx = blockIdx.x >> 3;
  const int wgid = (xcd < r8 ? xcd * (qq + 1) : r8 * (qq + 1) + (xcd - r8) * qq) + bidx;
  const int mb = wgid / EB_TILES;
  const int eb = wgid - mb * EB_TILES;
  const int m0 = mb * BM, e0 = eb * BN;

  // staging: chunk c = p*512 + t; row = p*128 + (t>>2); slot = t&3;
  // logical cb = slot ^ (row&3) = (t&3)^((t>>2)&3)  (src pre-swizzled)
  const int cbs = (t & 3) ^ ((t >> 2) & 3);
  const ushort* ag = A + (size_t)(m0 + (t >> 2)) * Kdim + cbs * 8;
  const ushort* bg = Bw + (size_t)(e0 + (t >> 2)) * Kdim + cbs * 8;

  const int lane = t & 63;
  const int wv = t >> 6;            // 8 waves: 4M x 2N
  const int wrow0 = (wv >> 1) * 64; // 0..192
  const int wcol0 = (wv & 1) * 64;  // 0/64
  const int l31 = lane & 31, hi = lane >> 5;
  int arow[2], brow[2];
#pragma unroll
  for (int i = 0; i < 2; ++i) {
    arow[i] = wrow0 + i * 32 + l31;
    brow[i] = wcol0 + i * 32 + l31;
  }

  f32x16 acc[2][2] = {};

  // prologue: tiles 0,1 (3 loads each)
#pragma unroll
  for (int pt = 0; pt < 2; ++pt) {
    const ushort* agk = ag + pt * 32;
    gload16(agk, &As[pt][t * 8]);
    gload16(agk + 128 * Kdim, &As[pt][(512 + t) * 8]);
    gload16(bg + pt * 32, &Bs[pt][t * 8]);
  }
  asm volatile("s_waitcnt vmcnt(3)\n\ts_barrier" ::: "memory"); // tile 0 landed
  __builtin_amdgcn_sched_barrier(0);

  ushort* pA0 = &As[0][0];
  ushort* pA1 = &As[1][0];
  ushort* pA2 = &As[2][0];
  ushort* pB0 = &Bs[0][0];
  ushort* pB1 = &Bs[1][0];
  ushort* pB2 = &Bs[2][0];

#pragma unroll 1
  for (int kb = 0; kb < KSTEPS - 2; ++kb) {
    // issue tile kb+2 into stage-2 buffers (they held tile kb-1; all reads of
    // kb-1 completed before the end-of-(kb-1) barrier)
    {
      const ushort* agk = ag + (kb + 2) * 32;
      gload16(agk, pA2 + t * 8);
      gload16(agk + 128 * Kdim, pA2 + (512 + t) * 8);
      gload16(bg + (kb + 2) * 32, pB2 + t * 8);
    }
    // ds_read tile kb fragments
    short8 a[2][2], b[2][2]; // [kc][frag]
#pragma unroll
    for (int kc = 0; kc < 2; ++kc) {
      const int cb = kc * 2 + hi;
#pragma unroll
      for (int i = 0; i < 2; ++i) {
        a[kc][i] = *(const short8*)&pA0[arow[i] * 32 + ((cb ^ (arow[i] & 3)) << 3)];
        b[kc][i] = *(const short8*)&pB0[brow[i] * 32 + ((cb ^ (brow[i] & 3)) << 3)];
      }
    }
    asm volatile("s_waitcnt lgkmcnt(0)" ::: "memory");
    __builtin_amdgcn_sched_barrier(0);
    __builtin_amdgcn_s_setprio(1);
#pragma unroll
    for (int kc = 0; kc < 2; ++kc)
#pragma unroll
      for (int mi = 0; mi < 2; ++mi)
#pragma unroll
        for (int ni = 0; ni < 2; ++ni)
          acc[mi][ni] = __builtin_amdgcn_mfma_f32_32x32x16_bf16(
              a[kc][mi], b[kc][ni], acc[mi][ni], 0, 0, 0);
    __builtin_amdgcn_s_setprio(0);
    __builtin_amdgcn_sched_barrier(0);
    // allow only this step's 3 newest (tile kb+2) -> tile kb+1 landed
    asm volatile("s_waitcnt vmcnt(3)\n\ts_barrier" ::: "memory");
    __builtin_amdgcn_sched_barrier(0);
    // rotate stages
    ushort* tA = pA0; pA0 = pA1; pA1 = pA2; pA2 = tA;
    ushort* tB = pB0; pB0 = pB1; pB1 = pB2; pB2 = tB;
  }

  // peeled steps kb = KSTEPS-2, KSTEPS-1 (no issue)
#pragma unroll
  for (int tail = 0; tail < 2; ++tail) {
    short8 a[2][2], b[2][2];
#pragma unroll
    for (int kc = 0; kc < 2; ++kc) {
      const int cb = kc * 2 + hi;
#pragma unroll
      for (int i = 0; i < 2; ++i) {
        a[kc][i] = *(const short8*)&pA0[arow[i] * 32 + ((cb ^ (arow[i] & 3)) << 3)];
        b[kc][i] = *(const short8*)&pB0[brow[i] * 32 + ((cb ^ (brow[i] & 3)) << 3)];
      }
    }
    asm volatile("s_waitcnt lgkmcnt(0)" ::: "memory");
    __builtin_amdgcn_sched_barrier(0);
#pragma unroll
    for (int kc = 0; kc < 2; ++kc)
#pragma unroll
      for (int mi = 0; mi < 2; ++mi)
#pragma unroll
        for (int ni = 0; ni < 2; ++ni)
          acc[mi][ni] = __builtin_amdgcn_mfma_f32_32x32x16_bf16(
              a[kc][mi], b[kc][ni], acc[mi][ni], 0, 0, 0);
    if (tail == 0) {
      // tile KSTEPS-1 was issued at kb=KSTEPS-3; nothing newer in flight
      asm volatile("s_waitcnt vmcnt(0)\n\ts_barrier" ::: "memory");
      __builtin_amdgcn_sched_barrier(0);
      ushort* tA = pA0; pA0 = pA1; pA1 = pA2; pA2 = tA;
      ushort* tB = pB0; pB0 = pB1; pB1 = pB2; pB2 = tB;
    }
  }

  // epilogue: scale + bias, absmax, store bf16 preout (or f32)
  // 32x32 C layout (r10-verified): col = lane&31, row = (r&3)+8*(r>>2)+4*hi
  float amax = 0.f;
#pragma unroll
  for (int ni = 0; ni < 2; ++ni) {
    const int e = e0 + wcol0 + ni * 32 + l31;
    const float s = w_sf[e], bo = bias_out[e];
#pragma unroll
    for (int mi = 0; mi < 2; ++mi) {
      const int mbase = m0 + wrow0 + mi * 32 + hi * 4;
#pragma unroll
      for (int r = 0; r < 16; ++r) {
        const int m = mbase + (r & 3) + ((r >> 2) << 3);
        float v = acc[mi][ni][r] * s + bo;
        amax = fmaxf(amax, fabsf(v));
        if (BF16OUT)
          pq[(size_t)m * Edim + e] = f2bf(v);
        else
          out[(size_t)m * Edim + e] = v;
      }
    }
  }
  // per-block reduce -> ONE plain store (no atomics)
#pragma unroll
  for (int off = 32; off > 0; off >>= 1)
    amax = fmaxf(amax, __shfl_xor(amax, off));
  if (lane == 0) sred[wv] = amax;
  __syncthreads();
  if (t == 0) {
    float m = sred[0];
#pragma unroll
    for (int i = 1; i < 8; ++i) m = fmaxf(m, sred[i]);
    amax_arr[blockIdx.x] = m;
  }
}

// ---------------- requantize from bf16 preout -> f32 out ----------------
__global__ void requant_bf16_kernel(const ushort* __restrict__ pq,
                                    float* __restrict__ out,
                                    const float* __restrict__ amax_arr,
                                    float* __restrict__ sf_out, int n8) {
  __shared__ float smax[4];
  const int t = threadIdx.x;
  float m = 0.f;
  for (int i = t; i < NWG; i += 256) m = fmaxf(m, amax_arr[i]);
#pragma unroll
  for (int off = 32; off > 0; off >>= 1) m = fmaxf(m, __shfl_xor(m, off));
  if ((t & 63) == 0) smax[t >> 6] = m;
  __syncthreads();
  m = fmaxf(fmaxf(smax[0], smax[1]), fmaxf(smax[2], smax[3]));

  const float act_sf = m / 127.0f;
  const float inv = 127.0f / m;
  const int idx = blockIdx.x * blockDim.x + t;
  if (idx == 0) *sf_out = act_sf;
  const short8* p8 = (const short8*)pq;
  const int stride = gridDim.x * blockDim.x;
  for (int i = idx; i < n8; i += stride) {
    short8 p = p8[i];
    float4v o0, o1;
    o0.x = rintf(bf2f((ushort)p[0]) * inv) * act_sf;
    o0.y = rintf(bf2f((ushort)p[1]) * inv) * act_sf;
    o0.z = rintf(bf2f((ushort)p[2]) * inv) * act_sf;
    o0.w = rintf(bf2f((ushort)p[3]) * inv) * act_sf;
    o1.x = rintf(bf2f((ushort)p[4]) * inv) * act_sf;
    o1.y = rintf(bf2f((ushort)p[5]) * inv) * act_sf;
    o1.z = rintf(bf2f((ushort)p[6]) * inv) * act_sf;
    o1.w = rintf(bf2f((ushort)p[7]) * inv) * act_sf;
    ((float4v*)out)[i * 2] = o0;
    ((float4v*)out)[i * 2 + 1] = o1;
  }
}

// ---------------- fallback: requantize f32 in place ----------------
__global__ void requant_f32_kernel(float* __restrict__ out,
                                   const float* __restrict__ amax_arr,
                                   float* __restrict__ sf_out, int n4) {
  __shared__ float smax[4];
  const int t = threadIdx.x;
  float m = 0.f;
  for (int i = t; i < NWG; i += 256) m = fmaxf(m, amax_arr[i]);
#pragma unroll
  for (int off = 32; off > 0; off >>= 1) m = fmaxf(m, __shfl_xor(m, off));
  if ((t & 63) == 0) smax[t >> 6] = m;
  __syncthreads();
  m = fmaxf(fmaxf(smax[0], smax[1]), fmaxf(smax[2], smax[3]));

  const float act_sf = m / 127.0f;
  const float inv = 127.0f / m;
  const int idx = blockIdx.x * blockDim.x + t;
  if (idx == 0) *sf_out = act_sf;
  float4v* o = (float4v*)out;
  const int stride = gridDim.x * blockDim.x;
  for (int i = idx; i < n4; i += stride) {
    float4v v = o[i];
    v.x = rintf(v.x * inv) * act_sf;
    v.y = rintf(v.y * inv) * act_sf;
    v.z = rintf(v.z * inv) * act_sf;
    v.w = rintf(v.w * inv) * act_sf;
    o[i] = v;
  }
}

extern "C" void kernel_launch(void* const* d_in, const int* in_sizes, int n_in,
                              void* d_out, int out_size, void* d_ws, size_t ws_size,
                              hipStream_t stream) {
  const float* x = (const float*)d_in[0];
  const float* weight = (const float*)d_in[1];
  const float* bias = (const float*)d_in[2];
  const float* sfin = (const float*)d_in[3];
  float* out = (float*)d_out;

  char* ws = (char*)d_ws;
  float* amax_arr = (float*)(ws + WS_AMAXARR);
  float* w_sf = (float*)(ws + WS_WSF);
  float* bias_out = (float*)(ws + WS_BIAS);
  ushort* w_int = (ushort*)(ws + WS_WINT);
  ushort* A = (ushort*)(ws + WS_APAT);
  ushort* pq = (ushort*)(ws + WS_PQ);

  const int n4 = (128 * 3 * 224 * 224) / 4;
  prep_patch_kernel<<<Edim + 2048, 256, 0, stream>>>(
      weight, bias, sfin, w_int, w_sf, bias_out, x, A, n4);

  const int nout = out_size - 1; // 25088*768
  if (ws_size >= WS_NEED) {
    gemm11_kernel<true><<<NWG, 512, 0, stream>>>(A, w_int, w_sf, bias_out,
                                                 nullptr, pq, amax_arr);
    requant_bf16_kernel<<<2048, 256, 0, stream>>>(pq, out, amax_arr,
                                                  out + nout, nout / 8);
  } else {
    gemm11_kernel<false><<<NWG, 512, 0, stream>>>(A, w_int, w_sf, bias_out,
                                                  out, nullptr, amax_arr);
    requant_f32_kernel<<<2048, 256, 0, stream>>>(out, amax_arr, out + nout,
                                                 nout / 4);
  }
}

// Round 15
// 88.397 us; speedup vs baseline: 1.1523x; 1.1523x over previous
//
#include <hip/hip_runtime.h>

typedef unsigned int uint;
typedef unsigned short ushort;
typedef __attribute__((ext_vector_type(8))) short short8;
typedef __attribute__((ext_vector_type(16))) float f32x16;
typedef __attribute__((ext_vector_type(4))) float float4v;
typedef __attribute__((ext_vector_type(4))) ushort ushort4v;

constexpr int Edim = 768;
constexpr int Kdim = 768;   // C*P*P
constexpr int Mdim = 25088; // B*Npatch
constexpr int BM = 256, BN = 128, BK = 64;
constexpr int KSTEPS = Kdim / BK;        // 12
constexpr int MB_TILES = Mdim / BM;      // 98
constexpr int EB_TILES = Edim / BN;      // 6
constexpr int NWG = MB_TILES * EB_TILES; // 588

// ws layout
constexpr size_t WS_AMAXARR = 0;            // NWG floats
constexpr size_t WS_WSF = 8192;
constexpr size_t WS_BIAS = 12288;
constexpr size_t WS_WINT = 16384;           // bf16 W [E][K]
constexpr size_t WS_APAT = 16384 + 1179648; // 25088*768*2 bf16 A
constexpr size_t WS_PQ = WS_APAT + (size_t)Mdim * Kdim * 2; // bf16 preout (native layout)
constexpr size_t WS_NEED = WS_PQ + (size_t)Mdim * Edim * 2;

// round-to-nearest-even f32 -> bf16
__device__ __forceinline__ ushort f2bf(float f) {
  uint u = __float_as_uint(f);
  return (ushort)((u + 0x7fffu + ((u >> 16) & 1u)) >> 16);
}
__device__ __forceinline__ float bf2f(ushort b) {
  return __uint_as_float(((uint)b) << 16);
}

__device__ __forceinline__ void gload16(const void* g, void* l) {
  auto gp = (const __attribute__((address_space(1))) uint*)g;
  auto lp = (__attribute__((address_space(3))) uint*)l;
  __builtin_amdgcn_global_load_lds(gp, lp, 16, 0, 0);
}

// ---------------- fused: weight quant (blocks 0..767) + patchify ------------
__global__ void prep_patch_kernel(const float* __restrict__ weight,
                                  const float* __restrict__ bias,
                                  const float* __restrict__ sfin,
                                  ushort* __restrict__ w_int,
                                  float* __restrict__ w_sf,
                                  float* __restrict__ bias_out,
                                  const float* __restrict__ x,
                                  ushort* __restrict__ A, int n4) {
  const int t = threadIdx.x;
  if (blockIdx.x < Edim) {
    __shared__ float red[256];
    const int e = blockIdx.x;
    const float* wrow = weight + e * Kdim;
    float mx = 0.f;
    for (int k = t; k < Kdim; k += 256) mx = fmaxf(mx, fabsf(wrow[k]));
    red[t] = mx;
    __syncthreads();
    for (int s = 128; s > 0; s >>= 1) {
      if (t < s) red[t] = fmaxf(red[t], red[t + s]);
      __syncthreads();
    }
    const float sf = red[0] / 127.0f;
    for (int k = t; k < Kdim; k += 256)
      w_int[e * Kdim + k] = f2bf(rintf(wrow[k] / sf));
    if (t == 0) {
      float conv = sf * sfin[0];
      w_sf[e] = sf;
      bias_out[e] = rintf(bias[e] / conv) * conv;
    }
  } else {
    const int nb = gridDim.x - Edim;
    const int stride = nb * 256;
    for (int i4 = (blockIdx.x - Edim) * 256 + t; i4 < n4; i4 += stride) {
      const int i = i4 * 4;
      const int w = i % 224;
      const int t1 = i / 224;
      const int h = t1 % 224;
      const int t2 = t1 / 224;
      const int c = t2 % 3;
      const int b = t2 / 3;
      float4v v = *(const float4v*)(x + i);
      ushort4v u;
      u.x = f2bf(v.x); u.y = f2bf(v.y); u.z = f2bf(v.z); u.w = f2bf(v.w);
      const int m = b * 196 + (h >> 4) * 14 + (w >> 4);
      const int d = c * 256 + (h & 15) * 16 + (w & 15);
      *(ushort4v*)(A + m * Kdim + d) = u;
    }
  }
}

// ---------------- GEMM: r10 structure + native-layout wide pq stores --------
// Identical staging/schedule to r10 (58.3us measured). Epilogue change only:
// BF16OUT: each thread stores its 64 bf16 values via 8 contiguous short8
// stores at pq[wgid*32768 + g*4096 + t*8] (wave = 1KB dense per instruction).
// The (m,e) un-permutation happens in requant_nat_kernel.
template <bool BF16OUT>
__global__ __launch_bounds__(512, 2) void gemm12_kernel(
    const ushort* __restrict__ A, const ushort* __restrict__ Bw,
    const float* __restrict__ w_sf, const float* __restrict__ bias_out,
    float* __restrict__ out, ushort* __restrict__ pq,
    float* __restrict__ amax_arr) {
  __shared__ __align__(16) ushort As[3][BM * BK]; // 3 x 32 KB
  __shared__ __align__(16) ushort Bs[3][BN * BK]; // 3 x 16 KB
  __shared__ float sred[8];

  const int t = threadIdx.x;
  // bijective XCD swizzle for NWG=588 (m204 variant)
  const int qq = NWG >> 3, r8 = NWG & 7;
  const int xcd = blockIdx.x & 7, bidx = blockIdx.x >> 3;
  const int wgid = (xcd < r8 ? xcd * (qq + 1) : r8 * (qq + 1) + (xcd - r8) * qq) + bidx;
  const int mb = wgid / EB_TILES;
  const int eb = wgid - mb * EB_TILES;
  const int m0 = mb * BM, e0 = eb * BN;

  // staging: chunk c = rr*512 + t; row = rr*64 + (t>>3); slot = t&7;
  // logical cb8 = (t&7)^((t>>3)&7)  (src pre-swizzled, dest linear)
  const int cbs = (t & 7) ^ ((t >> 3) & 7);
  const ushort* ag = A + (size_t)(m0 + (t >> 3)) * Kdim + cbs * 8;
  const ushort* bg = Bw + (size_t)(e0 + (t >> 3)) * Kdim + cbs * 8;

  const int lane = t & 63;
  const int wv = t >> 6;            // 8 waves: 4M x 2N
  const int wrow0 = (wv >> 1) * 64; // 0..192
  const int wcol0 = (wv & 1) * 64;  // 0/64
  const int l31 = lane & 31, hi = lane >> 5;
  int arow[2], brow[2];
#pragma unroll
  for (int i = 0; i < 2; ++i) {
    arow[i] = wrow0 + i * 32 + l31;
    brow[i] = wcol0 + i * 32 + l31;
  }

  f32x16 acc[2][2] = {};

  // prologue: tiles 0,1
#pragma unroll
  for (int pt = 0; pt < 2; ++pt) {
    const ushort* agk = ag + pt * 64;
#pragma unroll
    for (int rr = 0; rr < 4; ++rr)
      gload16(agk + rr * 64 * Kdim, &As[pt][(rr * 512 + t) * 8]);
#pragma unroll
    for (int rr = 0; rr < 2; ++rr)
      gload16(bg + pt * 64 + rr * 64 * Kdim, &Bs[pt][(rr * 512 + t) * 8]);
  }
  asm volatile("s_waitcnt vmcnt(6)\n\ts_barrier" ::: "memory"); // tile 0 landed
  __builtin_amdgcn_sched_barrier(0);

#pragma unroll
  for (int kb = 0; kb < KSTEPS; ++kb) {
    const int st = kb % 3;
    const int st2 = (kb + 2) % 3;

    // ---------------- phase A (kc = 0,1) ----------------
    if (kb + 2 < KSTEPS) { // stage first half of tile kb+2
      const ushort* agk = ag + (kb + 2) * 64;
      gload16(agk + 0 * 64 * Kdim, &As[st2][(0 * 512 + t) * 8]);
      gload16(agk + 1 * 64 * Kdim, &As[st2][(1 * 512 + t) * 8]);
      gload16(bg + (kb + 2) * 64 + 0 * 64 * Kdim, &Bs[st2][(0 * 512 + t) * 8]);
    }
    short8 a0[2][2], b0[2][2]; // [kc][frag]
#pragma unroll
    for (int kc = 0; kc < 2; ++kc) {
      const int cb = kc * 2 + hi;
#pragma unroll
      for (int i = 0; i < 2; ++i) {
        a0[kc][i] = *(const short8*)&As[st][arow[i] * 64 + ((cb ^ (arow[i] & 7)) << 3)];
        b0[kc][i] = *(const short8*)&Bs[st][brow[i] * 64 + ((cb ^ (brow[i] & 7)) << 3)];
      }
    }
    asm volatile("s_waitcnt lgkmcnt(0)" ::: "memory");
    __builtin_amdgcn_sched_barrier(0);
    __builtin_amdgcn_s_setprio(1);
#pragma unroll
    for (int kc = 0; kc < 2; ++kc)
#pragma unroll
      for (int mi = 0; mi < 2; ++mi)
#pragma unroll
        for (int ni = 0; ni < 2; ++ni)
          acc[mi][ni] = __builtin_amdgcn_mfma_f32_32x32x16_bf16(
              a0[kc][mi], b0[kc][ni], acc[mi][ni], 0, 0, 0);
    __builtin_amdgcn_s_setprio(0);
    // read phase-B frags BEFORE the mid barrier (same validated buffer)
    short8 a1[2][2], b1[2][2];
#pragma unroll
    for (int kc = 0; kc < 2; ++kc) {
      const int cb = (kc + 2) * 2 + hi;
#pragma unroll
      for (int i = 0; i < 2; ++i) {
        a1[kc][i] = *(const short8*)&As[st][arow[i] * 64 + ((cb ^ (arow[i] & 7)) << 3)];
        b1[kc][i] = *(const short8*)&Bs[st][brow[i] * 64 + ((cb ^ (brow[i] & 7)) << 3)];
      }
    }
    __builtin_amdgcn_s_barrier(); // rhythm barrier (no drain)

    // ---------------- phase B (kc = 2,3) ----------------
    if (kb + 2 < KSTEPS) { // stage second half of tile kb+2
      const ushort* agk = ag + (kb + 2) * 64;
      gload16(agk + 2 * 64 * Kdim, &As[st2][(2 * 512 + t) * 8]);
      gload16(agk + 3 * 64 * Kdim, &As[st2][(3 * 512 + t) * 8]);
      gload16(bg + (kb + 2) * 64 + 1 * 64 * Kdim, &Bs[st2][(1 * 512 + t) * 8]);
    }
    asm volatile("s_waitcnt lgkmcnt(0)" ::: "memory");
    __builtin_amdgcn_sched_barrier(0);
    __builtin_amdgcn_s_setprio(1);
#pragma unroll
    for (int kc = 0; kc < 2; ++kc)
#pragma unroll
      for (int mi = 0; mi < 2; ++mi)
#pragma unroll
        for (int ni = 0; ni < 2; ++ni)
          acc[mi][ni] = __builtin_amdgcn_mfma_f32_32x32x16_bf16(
              a1[kc][mi], b1[kc][ni], acc[mi][ni], 0, 0, 0);
    __builtin_amdgcn_s_setprio(0);

    if (kb < KSTEPS - 1) {
      __builtin_amdgcn_sched_barrier(0);
      if (kb + 2 < KSTEPS)
        asm volatile("s_waitcnt vmcnt(6)\n\ts_barrier" ::: "memory");
      else
        asm volatile("s_waitcnt vmcnt(0)\n\ts_barrier" ::: "memory");
      __builtin_amdgcn_sched_barrier(0);
    }
  }

  // epilogue
  float amax = 0.f;
  if (BF16OUT) {
    // native-layout: vals in (mi,ni,r) order, 8 contiguous short8 stores
    ushort vals[64];
    float sv[2], bv[2];
#pragma unroll
    for (int ni = 0; ni < 2; ++ni) {
      const int e = e0 + wcol0 + ni * 32 + l31;
      sv[ni] = w_sf[e];
      bv[ni] = bias_out[e];
    }
#pragma unroll
    for (int mi = 0; mi < 2; ++mi)
#pragma unroll
      for (int ni = 0; ni < 2; ++ni)
#pragma unroll
        for (int r = 0; r < 16; ++r) {
          float v = acc[mi][ni][r] * sv[ni] + bv[ni];
          amax = fmaxf(amax, fabsf(v));
          vals[(mi * 2 + ni) * 16 + r] = f2bf(v);
        }
    ushort* pqb = pq + (size_t)wgid * 32768;
#pragma unroll
    for (int g = 0; g < 8; ++g)
      *(short8*)(pqb + g * 4096 + t * 8) = *(const short8*)&vals[g * 8];
  } else {
    // fallback: direct f32 scatter (r10-style)
#pragma unroll
    for (int ni = 0; ni < 2; ++ni) {
      const int e = e0 + wcol0 + ni * 32 + l31;
      const float s = w_sf[e], bo = bias_out[e];
#pragma unroll
      for (int mi = 0; mi < 2; ++mi) {
        const int mbase = m0 + wrow0 + mi * 32 + hi * 4;
#pragma unroll
        for (int r = 0; r < 16; ++r) {
          const int m = mbase + (r & 3) + ((r >> 2) << 3);
          float v = acc[mi][ni][r] * s + bo;
          amax = fmaxf(amax, fabsf(v));
          out[(size_t)m * Edim + e] = v;
        }
      }
    }
  }
  // per-block reduce -> ONE plain store (no atomics)
#pragma unroll
  for (int off = 32; off > 0; off >>= 1)
    amax = fmaxf(amax, __shfl_xor(amax, off));
  if (lane == 0) sred[wv] = amax;
  __syncthreads();
  if (t == 0) {
    float m = sred[0];
#pragma unroll
    for (int i = 1; i < 8; ++i) m = fmaxf(m, sred[i]);
    amax_arr[blockIdx.x] = m;
  }
}

// ------- requantize from native-layout pq: coalesced read -> LDS transpose --
// One 256-thread block per gemm block (588). pq value (t_g, v) maps to:
//   wv=t_g>>6, lane=t_g&63, l31=lane&31, hi=lane>>5; mi=v>>5, ni=(v>>4)&1, r=v&15
//   m_local = (wv>>1)*64 + mi*32 + hi*4 + (r&3) + 8*(r>>2)
//   e_local = (wv&1)*64 + ni*32 + l31
__global__ __launch_bounds__(256) void requant_nat_kernel(
    const ushort* __restrict__ pq, float* __restrict__ out,
    const float* __restrict__ amax_arr, float* __restrict__ sf_out) {
  __shared__ ushort tile[BM * BN]; // 64 KB
  __shared__ float smax[4];
  const int t = threadIdx.x;
  // global amax reduce
  float m = 0.f;
  for (int i = t; i < NWG; i += 256) m = fmaxf(m, amax_arr[i]);
#pragma unroll
  for (int off = 32; off > 0; off >>= 1) m = fmaxf(m, __shfl_xor(m, off));
  if ((t & 63) == 0) smax[t >> 6] = m;
  __syncthreads();
  m = fmaxf(fmaxf(smax[0], smax[1]), fmaxf(smax[2], smax[3]));
  const float act_sf = m / 127.0f;
  const float inv = 127.0f / m;
  const int b = blockIdx.x;
  if (b == 0 && t == 0) *sf_out = act_sf;

  const ushort* src = pq + (size_t)b * 32768;
  // load (coalesced) + scatter to LDS
#pragma unroll
  for (int p = 0; p < 16; ++p) {
    short8 w = *(const short8*)(src + p * 2048 + t * 8);
    const int g = p >> 1;
    const int tg = ((p & 1) << 8) + t;
    const int wv = tg >> 6, lane = tg & 63;
    const int l31 = lane & 31, hi = lane >> 5;
    const int mbase = ((wv >> 1) << 6) + hi * 4;
    const int ebase = ((wv & 1) << 6) + l31;
#pragma unroll
    for (int j = 0; j < 8; ++j) {
      const int v = g * 8 + j;
      const int mi = v >> 5, ni = (v >> 4) & 1, r = v & 15;
      const int ml = mbase + mi * 32 + (r & 3) + ((r >> 2) << 3);
      const int el = ebase + ni * 32;
      tile[ml * BN + el] = (ushort)w[j];
    }
  }
  __syncthreads();
  // write out (coalesced float4)
  const int mb = b / EB_TILES, eb = b - mb * EB_TILES;
  const int m0 = mb * BM, e0 = eb * BN;
#pragma unroll
  for (int p2 = 0; p2 < 32; ++p2) {
    const int idx4 = p2 * 1024 + t * 4;
    const int ml = idx4 >> 7;        // /BN
    const int el = idx4 & 127;       // %BN
    ushort4v u = *(const ushort4v*)&tile[ml * BN + el];
    float4v o;
    o.x = rintf(bf2f(u.x) * inv) * act_sf;
    o.y = rintf(bf2f(u.y) * inv) * act_sf;
    o.z = rintf(bf2f(u.z) * inv) * act_sf;
    o.w = rintf(bf2f(u.w) * inv) * act_sf;
    *(float4v*)(out + (size_t)(m0 + ml) * Edim + e0 + el) = o;
  }
}

// ---------------- fallback: requantize f32 in place ----------------
__global__ void requant_f32_kernel(float* __restrict__ out,
                                   const float* __restrict__ amax_arr,
                                   float* __restrict__ sf_out, int n4) {
  __shared__ float smax[4];
  const int t = threadIdx.x;
  float m = 0.f;
  for (int i = t; i < NWG; i += 256) m = fmaxf(m, amax_arr[i]);
#pragma unroll
  for (int off = 32; off > 0; off >>= 1) m = fmaxf(m, __shfl_xor(m, off));
  if ((t & 63) == 0) smax[t >> 6] = m;
  __syncthreads();
  m = fmaxf(fmaxf(smax[0], smax[1]), fmaxf(smax[2], smax[3]));

  const float act_sf = m / 127.0f;
  const float inv = 127.0f / m;
  const int idx = blockIdx.x * blockDim.x + t;
  if (idx == 0) *sf_out = act_sf;
  float4v* o = (float4v*)out;
  const int stride = gridDim.x * blockDim.x;
  for (int i = idx; i < n4; i += stride) {
    float4v v = o[i];
    v.x = rintf(v.x * inv) * act_sf;
    v.y = rintf(v.y * inv) * act_sf;
    v.z = rintf(v.z * inv) * act_sf;
    v.w = rintf(v.w * inv) * act_sf;
    o[i] = v;
  }
}

extern "C" void kernel_launch(void* const* d_in, const int* in_sizes, int n_in,
                              void* d_out, int out_size, void* d_ws, size_t ws_size,
                              hipStream_t stream) {
  const float* x = (const float*)d_in[0];
  const float* weight = (const float*)d_in[1];
  const float* bias = (const float*)d_in[2];
  const float* sfin = (const float*)d_in[3];
  float* out = (float*)d_out;

  char* ws = (char*)d_ws;
  float* amax_arr = (float*)(ws + WS_AMAXARR);
  float* w_sf = (float*)(ws + WS_WSF);
  float* bias_out = (float*)(ws + WS_BIAS);
  ushort* w_int = (ushort*)(ws + WS_WINT);
  ushort* A = (ushort*)(ws + WS_APAT);
  ushort* pq = (ushort*)(ws + WS_PQ);

  const int n4 = (128 * 3 * 224 * 224) / 4;
  prep_patch_kernel<<<Edim + 2048, 256, 0, stream>>>(
      weight, bias, sfin, w_int, w_sf, bias_out, x, A, n4);

  const int nout = out_size - 1; // 25088*768
  if (ws_size >= WS_NEED) {
    gemm12_kernel<true><<<NWG, 512, 0, stream>>>(A, w_int, w_sf, bias_out,
                                                 nullptr, pq, amax_arr);
    requant_nat_kernel<<<NWG, 256, 0, stream>>>(pq, out, amax_arr, out + nout);
  } else {
    gemm12_kernel<false><<<NWG, 512, 0, stream>>>(A, w_int, w_sf, bias_out,
                                                  out, nullptr, amax_arr);
    requant_f32_kernel<<<2048, 256, 0, stream>>>(out, amax_arr, out + nout,
                                                 nout / 4);
  }
}